// Round 1
// baseline (5168.058 us; speedup 1.0000x reference)
//
#include <hip/hip_runtime.h>
#include <stdint.h>

typedef unsigned int u32;
typedef unsigned short u16;

constexpr int NB  = 4096;   // batch
constexpr int NT  = 56;     // encoder steps
constexpr int NS  = 28;     // decoder steps
constexpr int NH  = 126;    // hidden
constexpr int NHP = 128;    // padded hidden (storage/weights)
constexpr int NE  = 20;     // encoder feature
constexpr int ND  = 15;     // decoder feature
constexpr int NX  = 142;    // decoder GRU input = 1 + 15 + 126
constexpr int NXP = 144;    // padded

// workspace byte offsets (total ~120.3 MB)
constexpr size_t OFF_H    = 0;           // float[4096*126]      h state
constexpr size_t OFF_ENC  = 2064384;     // u16[56*4096*128]     enc_out bf16
constexpr size_t OFF_UO   = 60784640;    // u16[56*4096*128]     Uo bf16
constexpr size_t OFF_EWHH = 119504896;   // float[378*128]       enc Whh padded
constexpr size_t OFF_DWHH = 119698432;   // float[378*128]       dec Whh padded
constexpr size_t OFF_DWIH = 119891968;   // float[378*144]       dec Wih padded
constexpr size_t OFF_UW   = 120109696;   // float[126*128]       U_W padded
constexpr size_t OFF_WL   = 120174208;   // float[126*128]       Wl_W padded

__device__ __forceinline__ float fexp2(float x){ return __builtin_amdgcn_exp2f(x); }
__device__ __forceinline__ float frcp (float x){ return __builtin_amdgcn_rcpf(x); }
__device__ __forceinline__ float sigm (float x){ return frcp(1.f + fexp2(-1.4426950408889634f * x)); }
__device__ __forceinline__ float ftanh(float x){ return 1.f - 2.f * frcp(1.f + fexp2(2.8853900817779268f * x)); }
__device__ __forceinline__ float asf(u32 u){ union { u32 i; float f; } v; v.i = u; return v.f; }
__device__ __forceinline__ u32 f2bf(float f){ union { float f; u32 i; } v; v.f = f;
  return (v.i + 0x7fffu + ((v.i >> 16) & 1u)) >> 16; }
__device__ __forceinline__ u32 packbf(float lo, float hi){ return f2bf(lo) | (f2bf(hi) << 16); }

// ---------------- weight repack: zero-padded rows so all loads are aligned float4 ----------------
__global__ void k_prep(const float* __restrict__ eWhh, const float* __restrict__ dWhh,
                       const float* __restrict__ dWih, const float* __restrict__ UW,
                       const float* __restrict__ Wl, char* __restrict__ ws)
{
  float* oE = (float*)(ws + OFF_EWHH);
  float* oD = (float*)(ws + OFF_DWHH);
  float* oI = (float*)(ws + OFF_DWIH);
  float* oU = (float*)(ws + OFF_UW);
  float* oW = (float*)(ws + OFF_WL);
  const int n1 = 378 * 128, n3 = 378 * 144, n4 = 126 * 128;
  const int total = n1 + n1 + n3 + n4 + n4;
  for (int i = blockIdx.x * 256 + threadIdx.x; i < total; i += gridDim.x * 256) {
    int idx = i;
    if (idx < n1) { int r = idx >> 7, c = idx & 127; oE[idx] = (c < NH) ? eWhh[r*NH + c] : 0.f; continue; }
    idx -= n1;
    if (idx < n1) { int r = idx >> 7, c = idx & 127; oD[idx] = (c < NH) ? dWhh[r*NH + c] : 0.f; continue; }
    idx -= n1;
    if (idx < n3) { int r = idx / 144, c = idx % 144; oI[idx] = (c < NX) ? dWih[r*NX + c] : 0.f; continue; }
    idx -= n3;
    if (idx < n4) { int r = idx >> 7, c = idx & 127; oU[idx] = (c < NH) ? UW[r*NH + c] : 0.f; continue; }
    idx -= n4;
    { int r = idx >> 7, c = idx & 127; oW[idx] = (c < NH) ? Wl[r*NH + c] : 0.f; }
  }
}

// ---------------- init MLP: h0 = relu(ann@W1^T+b1)@W2^T+b2 ----------------
__global__ __launch_bounds__(256) void k_mlp(
    const float* __restrict__ ann, const float* __restrict__ W1, const float* __restrict__ b1,
    const float* __restrict__ W2, const float* __restrict__ b2, float* __restrict__ hstate)
{
  __shared__ float anns[32][33];
  __shared__ float t1s[32][101];
  const int tid = threadIdx.x;
  const int b0 = blockIdx.x * 32;
  for (int i = tid; i < 32 * 30; i += 256)
    anns[i / 30][i % 30] = ann[(b0 + i / 30) * 30 + (i % 30)];
  __syncthreads();
  const int b = tid & 31, rg = tid >> 5;
  for (int m = rg; m < 96; m += 8) {
    float a = b1[m];
    for (int k = 0; k < 30; ++k) a += W1[m * 30 + k] * anns[b][k];
    t1s[b][m] = fmaxf(a, 0.f);
  }
  __syncthreads();
  for (int j = rg; j < NH; j += 8) {
    float a = b2[j];
    for (int k = 0; k < 96; ++k) a += W2[j * 96 + k] * t1s[b][k];
    hstate[(b0 + b) * NH + j] = a;
  }
}

// ---------------- encoder: 56 GRU steps + fused Uo; block owns 8 batch rows ----------------
__global__ __launch_bounds__(256) void k_enc(
    const float* __restrict__ xenc, const float* __restrict__ Wih,
    const float* __restrict__ bih, const float* __restrict__ bhh,
    const float* __restrict__ WhhP, const float* __restrict__ UWp,
    const float* __restrict__ Ub, float* __restrict__ hstate,
    u16* __restrict__ enc_o, u16* __restrict__ uo_o)
{
  __shared__ __align__(16) float hBuf[2][8][132];
  __shared__ __align__(16) float xs[8][20];
  const int tid = threadIdx.x;
  const int b = tid & 7, rg = tid >> 3;
  const int b0 = blockIdx.x * 8;
  const int gb = b0 + b;
  const int j0 = rg * 4;                    // 4 gate-rows per thread; rg=31 -> only 2 valid
  int jr[4];
#pragma unroll
  for (int jj = 0; jj < 4; ++jj) jr[jj] = (j0 + jj < NH) ? (j0 + jj) : (NH - 1);

  float bir[4], biz[4], bin_[4], bhr[4], bhz[4], bhn_[4], ub4[4];
#pragma unroll
  for (int jj = 0; jj < 4; ++jj) {
    const int j = jr[jj];
    bir[jj] = bih[j]; biz[jj] = bih[NH + j]; bin_[jj] = bih[2 * NH + j];
    bhr[jj] = bhh[j]; bhz[jj] = bhh[NH + j]; bhn_[jj] = bhh[2 * NH + j];
    ub4[jj] = Ub[j];
  }

  for (int i = tid; i < 8 * NH; i += 256)
    hBuf[0][i / NH][i % NH] = hstate[(b0 + i / NH) * NH + (i % NH)];
  if (tid < 48) { const int bb = tid / 6, p = tid % 6; hBuf[0][bb][NH + p] = 0.f; hBuf[1][bb][NH + p] = 0.f; }

  for (int t = 0; t < NT; ++t) {
    for (int i = tid; i < 8 * NE; i += 256)
      xs[i / NE][i % NE] = xenc[(t * NB + b0 + i / NE) * NE + (i % NE)];
    __syncthreads();
    const float (*hc)[132] = hBuf[t & 1];
    float (*hn)[132] = hBuf[(t & 1) ^ 1];

    float ar[4], az[4], an[4], hr[4], hz[4], hnn[4];
#pragma unroll
    for (int jj = 0; jj < 4; ++jj) {
      ar[jj] = bir[jj]; az[jj] = biz[jj]; an[jj] = bin_[jj];
      hr[jj] = bhr[jj]; hz[jj] = bhz[jj]; hnn[jj] = bhn_[jj];
    }
#pragma unroll
    for (int k = 0; k < NE; k += 4) {
      const float4 xv = *(const float4*)&xs[b][k];
#pragma unroll
      for (int jj = 0; jj < 4; ++jj) {
        const float4 wr = *(const float4*)&Wih[jr[jj] * NE + k];
        const float4 wz = *(const float4*)&Wih[(NH + jr[jj]) * NE + k];
        const float4 wn = *(const float4*)&Wih[(2 * NH + jr[jj]) * NE + k];
        ar[jj] += wr.x*xv.x + wr.y*xv.y + wr.z*xv.z + wr.w*xv.w;
        az[jj] += wz.x*xv.x + wz.y*xv.y + wz.z*xv.z + wz.w*xv.w;
        an[jj] += wn.x*xv.x + wn.y*xv.y + wn.z*xv.z + wn.w*xv.w;
      }
    }
#pragma unroll 2
    for (int k = 0; k < NHP; k += 4) {
      const float4 hv = *(const float4*)&hc[b][k];
#pragma unroll
      for (int jj = 0; jj < 4; ++jj) {
        const float4 wr = *(const float4*)&WhhP[jr[jj] * NHP + k];
        const float4 wz = *(const float4*)&WhhP[(NH + jr[jj]) * NHP + k];
        const float4 wn = *(const float4*)&WhhP[(2 * NH + jr[jj]) * NHP + k];
        hr[jj]  += wr.x*hv.x + wr.y*hv.y + wr.z*hv.z + wr.w*hv.w;
        hz[jj]  += wz.x*hv.x + wz.y*hv.y + wz.z*hv.z + wz.w*hv.w;
        hnn[jj] += wn.x*hv.x + wn.y*hv.y + wn.z*hv.z + wn.w*hv.w;
      }
    }
    float h2v[4];
#pragma unroll
    for (int jj = 0; jj < 4; ++jj) {
      const float r = sigm(ar[jj] + hr[jj]);
      const float z = sigm(az[jj] + hz[jj]);
      const float n = ftanh(an[jj] + r * hnn[jj]);
      h2v[jj] = (1.f - z) * n + z * hc[b][jr[jj]];
      if (j0 + jj < NH) hn[b][j0 + jj] = h2v[jj];
    }
    __syncthreads();

    // Uo = h2 @ U_W^T + U_b (fused), plus bf16 stores of enc_out/Uo
    float uo[4];
#pragma unroll
    for (int jj = 0; jj < 4; ++jj) uo[jj] = ub4[jj];
#pragma unroll 4
    for (int k = 0; k < NHP; k += 4) {
      const float4 hv = *(const float4*)&hn[b][k];
#pragma unroll
      for (int jj = 0; jj < 4; ++jj) {
        const float4 u = *(const float4*)&UWp[jr[jj] * NHP + k];
        uo[jj] += u.x*hv.x + u.y*hv.y + u.z*hv.z + u.w*hv.w;
      }
    }
    const int base = (t * NB + gb) * NHP;
    *(u32*)&enc_o[base + j0]     = packbf(h2v[0], h2v[1]);
    *(u32*)&enc_o[base + j0 + 2] = (j0 < NH - 2) ? packbf(h2v[2], h2v[3]) : 0u;  // rg31 zeroes pads
    *(u32*)&uo_o [base + j0]     = packbf(uo[0], uo[1]);
    *(u32*)&uo_o [base + j0 + 2] = (j0 < NH - 2) ? packbf(uo[2], uo[3]) : 0u;
    if (t == NT - 1) {
#pragma unroll
      for (int jj = 0; jj < 4; ++jj)
        if (j0 + jj < NH) hstate[gb * NH + j0 + jj] = h2v[jj];
    }
  }
}

// ---------------- decoder: 28 steps of attention + GRU + readout ----------------
__global__ __launch_bounds__(256) void k_dec(
    const float* __restrict__ xdec, const float* __restrict__ xenc,
    const float* __restrict__ WihP, const float* __restrict__ WhhP,
    const float* __restrict__ bih, const float* __restrict__ bhh,
    const float* __restrict__ WlP, const float* __restrict__ Wlb,
    const float* __restrict__ Vw, const float* __restrict__ Vb,
    const float* __restrict__ how, const float* __restrict__ hob,
    const float* __restrict__ hstate,
    const u16* __restrict__ enc_o, const u16* __restrict__ uo_o,
    float* __restrict__ out)
{
  __shared__ __align__(16) float hBuf[2][8][132];
  __shared__ __align__(16) float WhS[8][132];
  __shared__ __align__(16) float xb[8][148];
  __shared__ float scS[NT][9];
  __shared__ __align__(16) float Vs[NHP];
  __shared__ float prevs[8];
  const int tid = threadIdx.x;
  const int b = tid & 7, rg = tid >> 3;
  const int b0 = blockIdx.x * 8;
  const int gb = b0 + b;
  const int j0 = rg * 4;
  int jr[4];
#pragma unroll
  for (int jj = 0; jj < 4; ++jj) jr[jj] = (j0 + jj < NH) ? (j0 + jj) : (NH - 1);

  float bir[4], biz[4], bin_[4], bhr[4], bhz[4], bhn_[4], wlb4[4];
#pragma unroll
  for (int jj = 0; jj < 4; ++jj) {
    const int j = jr[jj];
    bir[jj] = bih[j]; biz[jj] = bih[NH + j]; bin_[jj] = bih[2 * NH + j];
    bhr[jj] = bhh[j]; bhz[jj] = bhh[NH + j]; bhn_[jj] = bhh[2 * NH + j];
    wlb4[jj] = Wlb[j];
  }
  const float vb0 = Vb[0];
  const float hob0 = hob[0];

  for (int i = tid; i < 8 * NH; i += 256)
    hBuf[0][i / NH][i % NH] = hstate[(b0 + i / NH) * NH + (i % NH)];
  if (tid < 48)       { const int bb = tid / 6, p = tid % 6; hBuf[0][bb][NH + p] = 0.f; hBuf[1][bb][NH + p] = 0.f; }
  else if (tid < 96)  { const int q = tid - 48; WhS[q / 6][NH + q % 6] = 0.f; }
  else if (tid < 144) { const int q = tid - 96; xb[q / 6][NX + q % 6] = 0.f; }
  if (tid < NHP) Vs[tid] = (tid < NH) ? Vw[tid] : 0.f;
  if (tid >= 248) prevs[tid - 248] = xenc[((NT - 1) * NB + b0 + (tid - 248)) * NE];  // gt0
  __syncthreads();

  for (int s = 0; s < NS; ++s) {
    const float (*hc)[132] = hBuf[s & 1];
    float (*hx)[132] = hBuf[(s & 1) ^ 1];

    // phase 1: Wh = h @ Wl^T + Wlb ; stage dec_x + prev into x buffer
    float wa[4];
#pragma unroll
    for (int jj = 0; jj < 4; ++jj) wa[jj] = wlb4[jj];
#pragma unroll 4
    for (int k = 0; k < NHP; k += 4) {
      const float4 hv = *(const float4*)&hc[b][k];
#pragma unroll
      for (int jj = 0; jj < 4; ++jj) {
        const float4 w = *(const float4*)&WlP[jr[jj] * NHP + k];
        wa[jj] += w.x*hv.x + w.y*hv.y + w.z*hv.z + w.w*hv.w;
      }
    }
#pragma unroll
    for (int jj = 0; jj < 4; ++jj)
      if (j0 + jj < NH) WhS[b][j0 + jj] = wa[jj];
    if (tid < 120) { const int bb = tid / 15, e = tid % 15; xb[bb][1 + e] = xdec[(s * NB + b0 + bb) * ND + e]; }
    else if (tid < 128) xb[tid - 120][0] = prevs[tid - 120];
    __syncthreads();

    // phase 2: scores[t][b] = sum_h tanh(Uo + Wh) * V + Vb   (t split over row-groups)
    for (int t = rg; t < NT; t += 32) {
      const uint4* up = (const uint4*)&uo_o[(t * NB + gb) * NHP];
      float acc = 0.f;
#pragma unroll 2
      for (int k = 0; k < NHP; k += 8) {
        const uint4 q = up[k >> 3];
        const float4 w0 = *(const float4*)&WhS[b][k];
        const float4 w1 = *(const float4*)&WhS[b][k + 4];
        const float4 v0 = *(const float4*)&Vs[k];
        const float4 v1 = *(const float4*)&Vs[k + 4];
        acc += ftanh(asf(q.x << 16)          + w0.x) * v0.x;
        acc += ftanh(asf(q.x & 0xffff0000u)  + w0.y) * v0.y;
        acc += ftanh(asf(q.y << 16)          + w0.z) * v0.z;
        acc += ftanh(asf(q.y & 0xffff0000u)  + w0.w) * v0.w;
        acc += ftanh(asf(q.z << 16)          + w1.x) * v1.x;
        acc += ftanh(asf(q.z & 0xffff0000u)  + w1.y) * v1.y;
        acc += ftanh(asf(q.w << 16)          + w1.z) * v1.z;
        acc += ftanh(asf(q.w & 0xffff0000u)  + w1.w) * v1.w;
      }
      scS[t][b] = acc + vb0;
    }
    __syncthreads();

    // phase 3: softmax over t + attn for this thread's 4 h-columns (single fused pass)
    float m = -1e30f;
    for (int t = 0; t < NT; ++t) m = fmaxf(m, scS[t][b]);
    float Z = 0.f, ac0 = 0.f, ac1 = 0.f, ac2 = 0.f, ac3 = 0.f;
#pragma unroll 8
    for (int t = 0; t < NT; ++t) {
      const float e = fexp2(1.4426950408889634f * (scS[t][b] - m));
      Z += e;
      const uint2 q = *(const uint2*)&enc_o[(t * NB + gb) * NHP + j0];
      ac0 += e * asf(q.x << 16);
      ac1 += e * asf(q.x & 0xffff0000u);
      ac2 += e * asf(q.y << 16);
      ac3 += e * asf(q.y & 0xffff0000u);
    }
    const float iZ = frcp(Z);
    if (j0     < NH) xb[b][16 + j0]     = ac0 * iZ;
    if (j0 + 1 < NH) xb[b][16 + j0 + 1] = ac1 * iZ;
    if (j0 + 2 < NH) xb[b][16 + j0 + 2] = ac2 * iZ;
    if (j0 + 3 < NH) xb[b][16 + j0 + 3] = ac3 * iZ;
    __syncthreads();

    // phase 4: GRU step on x=[prev, dec_x, attn]
    float ar[4], az[4], an[4], hr4[4], hz4[4], hn4[4];
#pragma unroll
    for (int jj = 0; jj < 4; ++jj) {
      ar[jj] = bir[jj]; az[jj] = biz[jj]; an[jj] = bin_[jj];
      hr4[jj] = bhr[jj]; hz4[jj] = bhz[jj]; hn4[jj] = bhn_[jj];
    }
#pragma unroll 2
    for (int k = 0; k < NXP; k += 4) {
      const float4 xv = *(const float4*)&xb[b][k];
#pragma unroll
      for (int jj = 0; jj < 4; ++jj) {
        const float4 wr = *(const float4*)&WihP[jr[jj] * NXP + k];
        const float4 wz = *(const float4*)&WihP[(NH + jr[jj]) * NXP + k];
        const float4 wn = *(const float4*)&WihP[(2 * NH + jr[jj]) * NXP + k];
        ar[jj] += wr.x*xv.x + wr.y*xv.y + wr.z*xv.z + wr.w*xv.w;
        az[jj] += wz.x*xv.x + wz.y*xv.y + wz.z*xv.z + wz.w*xv.w;
        an[jj] += wn.x*xv.x + wn.y*xv.y + wn.z*xv.z + wn.w*xv.w;
      }
    }
#pragma unroll 2
    for (int k = 0; k < NHP; k += 4) {
      const float4 hv = *(const float4*)&hc[b][k];
#pragma unroll
      for (int jj = 0; jj < 4; ++jj) {
        const float4 wr = *(const float4*)&WhhP[jr[jj] * NHP + k];
        const float4 wz = *(const float4*)&WhhP[(NH + jr[jj]) * NHP + k];
        const float4 wn = *(const float4*)&WhhP[(2 * NH + jr[jj]) * NHP + k];
        hr4[jj] += wr.x*hv.x + wr.y*hv.y + wr.z*hv.z + wr.w*hv.w;
        hz4[jj] += wz.x*hv.x + wz.y*hv.y + wz.z*hv.z + wz.w*hv.w;
        hn4[jj] += wn.x*hv.x + wn.y*hv.y + wn.z*hv.z + wn.w*hv.w;
      }
    }
#pragma unroll
    for (int jj = 0; jj < 4; ++jj) {
      const float r = sigm(ar[jj] + hr4[jj]);
      const float z = sigm(az[jj] + hz4[jj]);
      const float n = ftanh(an[jj] + r * hn4[jj]);
      const float h2 = (1.f - z) * n + z * hc[b][jr[jj]];
      if (j0 + jj < NH) hx[b][j0 + jj] = h2;
    }
    __syncthreads();

    // phase 5: out = h2 @ h2o^T + b ; becomes next prev
    if (tid < 8) {
      float o = hob0;
      for (int k = 0; k < NH; ++k) o += how[k] * hx[tid][k];
      out[s * NB + b0 + tid] = o;
      prevs[tid] = o;
    }
    __syncthreads();
  }
}

extern "C" void kernel_launch(void* const* d_in, const int* in_sizes, int n_in,
                              void* d_out, int out_size, void* d_ws, size_t ws_size,
                              hipStream_t stream)
{
  const float* ann   = (const float*)d_in[0];
  const float* xenc  = (const float*)d_in[1];
  const float* xdec  = (const float*)d_in[2];
  const float* W1    = (const float*)d_in[3];
  const float* b1    = (const float*)d_in[4];
  const float* W2    = (const float*)d_in[5];
  const float* b2    = (const float*)d_in[6];
  const float* eWih  = (const float*)d_in[7];
  const float* eWhh  = (const float*)d_in[8];
  const float* ebih  = (const float*)d_in[9];
  const float* ebhh  = (const float*)d_in[10];
  const float* dWih  = (const float*)d_in[11];
  const float* dWhh  = (const float*)d_in[12];
  const float* dbih  = (const float*)d_in[13];
  const float* dbhh  = (const float*)d_in[14];
  const float* UW    = (const float*)d_in[15];
  const float* Ubias = (const float*)d_in[16];
  const float* Wl    = (const float*)d_in[17];
  const float* Wlb   = (const float*)d_in[18];
  const float* Vw    = (const float*)d_in[19];
  const float* Vb    = (const float*)d_in[20];
  const float* how   = (const float*)d_in[21];
  const float* hob   = (const float*)d_in[22];

  char* ws = (char*)d_ws;
  float* hstate = (float*)(ws + OFF_H);
  u16*   enc_o  = (u16*)(ws + OFF_ENC);
  u16*   uo_o   = (u16*)(ws + OFF_UO);
  float* pEWhh  = (float*)(ws + OFF_EWHH);
  float* pDWhh  = (float*)(ws + OFF_DWHH);
  float* pDWih  = (float*)(ws + OFF_DWIH);
  float* pUW    = (float*)(ws + OFF_UW);
  float* pWl    = (float*)(ws + OFF_WL);

  k_prep<<<720, 256, 0, stream>>>(eWhh, dWhh, dWih, UW, Wl, ws);
  k_mlp <<<128, 256, 0, stream>>>(ann, W1, b1, W2, b2, hstate);
  k_enc <<<512, 256, 0, stream>>>(xenc, eWih, ebih, ebhh, pEWhh, pUW, Ubias,
                                  hstate, enc_o, uo_o);
  k_dec <<<512, 256, 0, stream>>>(xdec, xenc, pDWih, pDWhh, dbih, dbhh,
                                  pWl, Wlb, Vw, Vb, how, hob, hstate,
                                  enc_o, uo_o, (float*)d_out);
}

// Round 2
// 4812.577 us; speedup vs baseline: 1.0739x; 1.0739x over previous
//
#include <hip/hip_runtime.h>
#include <stdint.h>

typedef unsigned int u32;
typedef unsigned short u16;

constexpr int NB  = 4096;   // batch
constexpr int NT  = 56;     // encoder steps
constexpr int NS  = 28;     // decoder steps
constexpr int NH  = 126;    // hidden
constexpr int NHP = 128;    // padded hidden (storage/weights)
constexpr int NE  = 20;     // encoder feature
constexpr int ND  = 15;     // decoder feature
constexpr int NX  = 142;    // decoder GRU input = 1 + 15 + 126
constexpr int NXP = 144;    // padded

// workspace byte offsets (total ~120.3 MB)
constexpr size_t OFF_H    = 0;           // float[4096*126]      h state
constexpr size_t OFF_ENC  = 2064384;     // u16[56*4096*128]     enc_out bf16
constexpr size_t OFF_UO   = 60784640;    // u16[56*4096*128]     Uo bf16
constexpr size_t OFF_EWHH = 119504896;   // float[378*128]       enc Whh padded
constexpr size_t OFF_DWHH = 119698432;   // float[378*128]       dec Whh padded
constexpr size_t OFF_DWIH = 119891968;   // float[378*144]       dec Wih padded
constexpr size_t OFF_UW   = 120109696;   // float[126*128]       U_W padded
constexpr size_t OFF_WL   = 120174208;   // float[126*128]       Wl_W padded

__device__ __forceinline__ float fexp2(float x){ return __builtin_amdgcn_exp2f(x); }
__device__ __forceinline__ float frcp (float x){ return __builtin_amdgcn_rcpf(x); }
__device__ __forceinline__ float sigm (float x){ return frcp(1.f + fexp2(-1.4426950408889634f * x)); }
__device__ __forceinline__ float ftanh(float x){ return 1.f - 2.f * frcp(1.f + fexp2(2.8853900817779268f * x)); }
__device__ __forceinline__ float asf(u32 u){ union { u32 i; float f; } v; v.i = u; return v.f; }
__device__ __forceinline__ u32 f2bf(float f){ union { float f; u32 i; } v; v.f = f;
  return (v.i + 0x7fffu + ((v.i >> 16) & 1u)) >> 16; }
__device__ __forceinline__ u32 packbf(float lo, float hi){ return f2bf(lo) | (f2bf(hi) << 16); }

// ---------------- weight repack: zero-padded rows so all loads are aligned float4 ----------------
__global__ void k_prep(const float* __restrict__ eWhh, const float* __restrict__ dWhh,
                       const float* __restrict__ dWih, const float* __restrict__ UW,
                       const float* __restrict__ Wl, char* __restrict__ ws)
{
  float* oE = (float*)(ws + OFF_EWHH);
  float* oD = (float*)(ws + OFF_DWHH);
  float* oI = (float*)(ws + OFF_DWIH);
  float* oU = (float*)(ws + OFF_UW);
  float* oW = (float*)(ws + OFF_WL);
  const int n1 = 378 * 128, n3 = 378 * 144, n4 = 126 * 128;
  const int total = n1 + n1 + n3 + n4 + n4;
  for (int i = blockIdx.x * 256 + threadIdx.x; i < total; i += gridDim.x * 256) {
    int idx = i;
    if (idx < n1) { int r = idx >> 7, c = idx & 127; oE[idx] = (c < NH) ? eWhh[r*NH + c] : 0.f; continue; }
    idx -= n1;
    if (idx < n1) { int r = idx >> 7, c = idx & 127; oD[idx] = (c < NH) ? dWhh[r*NH + c] : 0.f; continue; }
    idx -= n1;
    if (idx < n3) { int r = idx / 144, c = idx % 144; oI[idx] = (c < NX) ? dWih[r*NX + c] : 0.f; continue; }
    idx -= n3;
    if (idx < n4) { int r = idx >> 7, c = idx & 127; oU[idx] = (c < NH) ? UW[r*NH + c] : 0.f; continue; }
    idx -= n4;
    { int r = idx >> 7, c = idx & 127; oW[idx] = (c < NH) ? Wl[r*NH + c] : 0.f; }
  }
}

// ---------------- init MLP: h0 = relu(ann@W1^T+b1)@W2^T+b2 ----------------
__global__ __launch_bounds__(256) void k_mlp(
    const float* __restrict__ ann, const float* __restrict__ W1, const float* __restrict__ b1,
    const float* __restrict__ W2, const float* __restrict__ b2, float* __restrict__ hstate)
{
  __shared__ float anns[32][33];
  __shared__ float t1s[32][101];
  const int tid = threadIdx.x;
  const int b0 = blockIdx.x * 32;
  for (int i = tid; i < 32 * 30; i += 256)
    anns[i / 30][i % 30] = ann[(b0 + i / 30) * 30 + (i % 30)];
  __syncthreads();
  const int b = tid & 31, rg = tid >> 5;
  for (int m = rg; m < 96; m += 8) {
    float a = b1[m];
    for (int k = 0; k < 30; ++k) a += W1[m * 30 + k] * anns[b][k];
    t1s[b][m] = fmaxf(a, 0.f);
  }
  __syncthreads();
  for (int j = rg; j < NH; j += 8) {
    float a = b2[j];
    for (int k = 0; k < 96; ++k) a += W2[j * 96 + k] * t1s[b][k];
    hstate[(b0 + b) * NH + j] = a;
  }
}

// ---------------- encoder: 56 GRU steps + fused Uo; block owns 8 batch rows ----------------
// 512 threads: b = tid&7 (8 batch rows), rg = tid>>3 (64 groups x 2 gate-rows)
__global__ __launch_bounds__(512) void k_enc(
    const float* __restrict__ xenc, const float* __restrict__ Wih,
    const float* __restrict__ bih, const float* __restrict__ bhh,
    const float* __restrict__ WhhP, const float* __restrict__ UWp,
    const float* __restrict__ Ub, float* __restrict__ hstate,
    u16* __restrict__ enc_o, u16* __restrict__ uo_o)
{
  __shared__ __align__(16) float hBuf[2][8][132];
  __shared__ __align__(16) float xs[8][20];
  const int tid = threadIdx.x;
  const int b = tid & 7, rg = tid >> 3;   // rg 0..63
  const int b0 = blockIdx.x * 8;
  const int gb = b0 + b;
  const int j0 = rg * 2;                  // 2 gate-rows per thread; rg=63 -> both pad
  int jr[2];
#pragma unroll
  for (int jj = 0; jj < 2; ++jj) jr[jj] = (j0 + jj < NH) ? (j0 + jj) : (NH - 1);

  float bir[2], biz[2], bin_[2], bhr[2], bhz[2], bhn_[2], ub2[2];
#pragma unroll
  for (int jj = 0; jj < 2; ++jj) {
    const int j = jr[jj];
    bir[jj] = bih[j]; biz[jj] = bih[NH + j]; bin_[jj] = bih[2 * NH + j];
    bhr[jj] = bhh[j]; bhz[jj] = bhh[NH + j]; bhn_[jj] = bhh[2 * NH + j];
    ub2[jj] = Ub[j];
  }

  for (int i = tid; i < 8 * NH; i += 512)
    hBuf[0][i / NH][i % NH] = hstate[(b0 + i / NH) * NH + (i % NH)];
  if (tid < 48) { const int bb = tid / 6, p = tid % 6; hBuf[0][bb][NH + p] = 0.f; hBuf[1][bb][NH + p] = 0.f; }

  for (int t = 0; t < NT; ++t) {
    if (tid < 8 * NE) xs[tid / NE][tid % NE] = xenc[(t * NB + b0 + tid / NE) * NE + (tid % NE)];
    __syncthreads();
    const float (*hc)[132] = hBuf[t & 1];
    float (*hn)[132] = hBuf[(t & 1) ^ 1];

    float ar[2], az[2], an[2], hr[2], hz[2], hnn[2];
#pragma unroll
    for (int jj = 0; jj < 2; ++jj) {
      ar[jj] = bir[jj]; az[jj] = biz[jj]; an[jj] = bin_[jj];
      hr[jj] = bhr[jj]; hz[jj] = bhz[jj]; hnn[jj] = bhn_[jj];
    }
#pragma unroll
    for (int k = 0; k < NE; k += 4) {
      const float4 xv = *(const float4*)&xs[b][k];
#pragma unroll
      for (int jj = 0; jj < 2; ++jj) {
        const float4 wr = *(const float4*)&Wih[jr[jj] * NE + k];
        const float4 wz = *(const float4*)&Wih[(NH + jr[jj]) * NE + k];
        const float4 wn = *(const float4*)&Wih[(2 * NH + jr[jj]) * NE + k];
        ar[jj] += wr.x*xv.x + wr.y*xv.y + wr.z*xv.z + wr.w*xv.w;
        az[jj] += wz.x*xv.x + wz.y*xv.y + wz.z*xv.z + wz.w*xv.w;
        an[jj] += wn.x*xv.x + wn.y*xv.y + wn.z*xv.z + wn.w*xv.w;
      }
    }
#pragma unroll 4
    for (int k = 0; k < NHP; k += 4) {
      const float4 hv = *(const float4*)&hc[b][k];
#pragma unroll
      for (int jj = 0; jj < 2; ++jj) {
        const float4 wr = *(const float4*)&WhhP[jr[jj] * NHP + k];
        const float4 wz = *(const float4*)&WhhP[(NH + jr[jj]) * NHP + k];
        const float4 wn = *(const float4*)&WhhP[(2 * NH + jr[jj]) * NHP + k];
        hr[jj]  += wr.x*hv.x + wr.y*hv.y + wr.z*hv.z + wr.w*hv.w;
        hz[jj]  += wz.x*hv.x + wz.y*hv.y + wz.z*hv.z + wz.w*hv.w;
        hnn[jj] += wn.x*hv.x + wn.y*hv.y + wn.z*hv.z + wn.w*hv.w;
      }
    }
    float h2v[2];
#pragma unroll
    for (int jj = 0; jj < 2; ++jj) {
      const float r = sigm(ar[jj] + hr[jj]);
      const float z = sigm(az[jj] + hz[jj]);
      const float n = ftanh(an[jj] + r * hnn[jj]);
      h2v[jj] = (1.f - z) * n + z * hc[b][jr[jj]];
      if (j0 + jj < NH) hn[b][j0 + jj] = h2v[jj];
    }
    __syncthreads();

    // Uo = h2 @ U_W^T + U_b (fused), plus bf16 stores of enc_out/Uo
    float uo[2];
#pragma unroll
    for (int jj = 0; jj < 2; ++jj) uo[jj] = ub2[jj];
#pragma unroll 4
    for (int k = 0; k < NHP; k += 4) {
      const float4 hv = *(const float4*)&hn[b][k];
#pragma unroll
      for (int jj = 0; jj < 2; ++jj) {
        const float4 u = *(const float4*)&UWp[jr[jj] * NHP + k];
        uo[jj] += u.x*hv.x + u.y*hv.y + u.z*hv.z + u.w*hv.w;
      }
    }
    const int base = (t * NB + gb) * NHP;
    *(u32*)&enc_o[base + j0] = (j0 < NH) ? packbf(h2v[0], h2v[1]) : 0u;  // rg63 zeroes pads
    *(u32*)&uo_o [base + j0] = (j0 < NH) ? packbf(uo[0], uo[1])   : 0u;
    if (t == NT - 1) {
#pragma unroll
      for (int jj = 0; jj < 2; ++jj)
        if (j0 + jj < NH) hstate[gb * NH + j0 + jj] = h2v[jj];
    }
  }
}

// ---------------- decoder: 28 steps of attention + GRU + readout ----------------
__global__ __launch_bounds__(512) void k_dec(
    const float* __restrict__ xdec, const float* __restrict__ xenc,
    const float* __restrict__ WihP, const float* __restrict__ WhhP,
    const float* __restrict__ bih, const float* __restrict__ bhh,
    const float* __restrict__ WlP, const float* __restrict__ Wlb,
    const float* __restrict__ Vw, const float* __restrict__ Vb,
    const float* __restrict__ how, const float* __restrict__ hob,
    const float* __restrict__ hstate,
    const u16* __restrict__ enc_o, const u16* __restrict__ uo_o,
    float* __restrict__ out)
{
  __shared__ __align__(16) float hBuf[2][8][132];
  __shared__ __align__(16) float WhS[8][132];
  __shared__ __align__(16) float xb[8][148];
  __shared__ float scS[NT][9];
  __shared__ __align__(16) float Vs[NHP];
  __shared__ __align__(16) float hows[NHP];
  __shared__ float prevs[8];
  const int tid = threadIdx.x;
  const int b = tid & 7, rg = tid >> 3;   // rg 0..63
  const int b0 = blockIdx.x * 8;
  const int gb = b0 + b;
  const int j0 = rg * 2;
  int jr[2];
#pragma unroll
  for (int jj = 0; jj < 2; ++jj) jr[jj] = (j0 + jj < NH) ? (j0 + jj) : (NH - 1);

  float bir[2], biz[2], bin_[2], bhr[2], bhz[2], bhn_[2], wlb2[2];
#pragma unroll
  for (int jj = 0; jj < 2; ++jj) {
    const int j = jr[jj];
    bir[jj] = bih[j]; biz[jj] = bih[NH + j]; bin_[jj] = bih[2 * NH + j];
    bhr[jj] = bhh[j]; bhz[jj] = bhh[NH + j]; bhn_[jj] = bhh[2 * NH + j];
    wlb2[jj] = Wlb[j];
  }
  const float vb0 = Vb[0];
  const float hob0 = hob[0];

  for (int i = tid; i < 8 * NH; i += 512)
    hBuf[0][i / NH][i % NH] = hstate[(b0 + i / NH) * NH + (i % NH)];
  if (tid < 48)       { const int bb = tid / 6, p = tid % 6; hBuf[0][bb][NH + p] = 0.f; hBuf[1][bb][NH + p] = 0.f; }
  else if (tid < 96)  { const int q = tid - 48; WhS[q / 6][NH + q % 6] = 0.f; }
  else if (tid < 144) { const int q = tid - 96; xb[q / 6][NX + q % 6] = 0.f; }
  if (tid < NHP) Vs[tid] = (tid < NH) ? Vw[tid] : 0.f;
  else if (tid < 2 * NHP) hows[tid - NHP] = (tid - NHP < NH) ? how[tid - NHP] : 0.f;
  if (tid >= 504) prevs[tid - 504] = xenc[((NT - 1) * NB + b0 + (tid - 504)) * NE];  // gt0
  __syncthreads();

  for (int s = 0; s < NS; ++s) {
    const float (*hc)[132] = hBuf[s & 1];
    float (*hx)[132] = hBuf[(s & 1) ^ 1];

    // phase 1: Wh = h @ Wl^T + Wlb ; stage dec_x + prev into x buffer
    float wa[2];
#pragma unroll
    for (int jj = 0; jj < 2; ++jj) wa[jj] = wlb2[jj];
#pragma unroll 4
    for (int k = 0; k < NHP; k += 4) {
      const float4 hv = *(const float4*)&hc[b][k];
#pragma unroll
      for (int jj = 0; jj < 2; ++jj) {
        const float4 w = *(const float4*)&WlP[jr[jj] * NHP + k];
        wa[jj] += w.x*hv.x + w.y*hv.y + w.z*hv.z + w.w*hv.w;
      }
    }
#pragma unroll
    for (int jj = 0; jj < 2; ++jj)
      if (j0 + jj < NH) WhS[b][j0 + jj] = wa[jj];
    if (tid < 120) { const int bb = tid / 15, e = tid % 15; xb[bb][1 + e] = xdec[(s * NB + b0 + bb) * ND + e]; }
    else if (tid < 128) xb[tid - 120][0] = prevs[tid - 120];
    __syncthreads();

    // phase 2: scores[t][b] = sum_h tanh(Uo + Wh) * V + Vb   (one t per row-group)
    if (rg < NT) {
      const int t = rg;
      const uint4* up = (const uint4*)&uo_o[(t * NB + gb) * NHP];
      float acc = 0.f;
#pragma unroll 2
      for (int k = 0; k < NHP; k += 8) {
        const uint4 q = up[k >> 3];
        const float4 w0 = *(const float4*)&WhS[b][k];
        const float4 w1 = *(const float4*)&WhS[b][k + 4];
        const float4 v0 = *(const float4*)&Vs[k];
        const float4 v1 = *(const float4*)&Vs[k + 4];
        acc += ftanh(asf(q.x << 16)          + w0.x) * v0.x;
        acc += ftanh(asf(q.x & 0xffff0000u)  + w0.y) * v0.y;
        acc += ftanh(asf(q.y << 16)          + w0.z) * v0.z;
        acc += ftanh(asf(q.y & 0xffff0000u)  + w0.w) * v0.w;
        acc += ftanh(asf(q.z << 16)          + w1.x) * v1.x;
        acc += ftanh(asf(q.z & 0xffff0000u)  + w1.y) * v1.y;
        acc += ftanh(asf(q.w << 16)          + w1.z) * v1.z;
        acc += ftanh(asf(q.w & 0xffff0000u)  + w1.w) * v1.w;
      }
      scS[t][b] = acc + vb0;
    }
    __syncthreads();

    // phase 3: softmax over t + attn for this thread's 2 h-columns (single fused pass)
    float m = -1e30f;
    for (int t = 0; t < NT; ++t) m = fmaxf(m, scS[t][b]);
    float Z = 0.f, ac0 = 0.f, ac1 = 0.f;
#pragma unroll 8
    for (int t = 0; t < NT; ++t) {
      const float e = fexp2(1.4426950408889634f * (scS[t][b] - m));
      Z += e;
      const u32 q = *(const u32*)&enc_o[(t * NB + gb) * NHP + j0];
      ac0 += e * asf(q << 16);
      ac1 += e * asf(q & 0xffff0000u);
    }
    const float iZ = frcp(Z);
    if (j0     < NH) xb[b][16 + j0]     = ac0 * iZ;
    if (j0 + 1 < NH) xb[b][16 + j0 + 1] = ac1 * iZ;
    __syncthreads();

    // phase 4: GRU step on x=[prev, dec_x, attn]
    float ar[2], az[2], an[2], hr2[2], hz2[2], hn2[2];
#pragma unroll
    for (int jj = 0; jj < 2; ++jj) {
      ar[jj] = bir[jj]; az[jj] = biz[jj]; an[jj] = bin_[jj];
      hr2[jj] = bhr[jj]; hz2[jj] = bhz[jj]; hn2[jj] = bhn_[jj];
    }
#pragma unroll 4
    for (int k = 0; k < NXP; k += 4) {
      const float4 xv = *(const float4*)&xb[b][k];
#pragma unroll
      for (int jj = 0; jj < 2; ++jj) {
        const float4 wr = *(const float4*)&WihP[jr[jj] * NXP + k];
        const float4 wz = *(const float4*)&WihP[(NH + jr[jj]) * NXP + k];
        const float4 wn = *(const float4*)&WihP[(2 * NH + jr[jj]) * NXP + k];
        ar[jj] += wr.x*xv.x + wr.y*xv.y + wr.z*xv.z + wr.w*xv.w;
        az[jj] += wz.x*xv.x + wz.y*xv.y + wz.z*xv.z + wz.w*xv.w;
        an[jj] += wn.x*xv.x + wn.y*xv.y + wn.z*xv.z + wn.w*xv.w;
      }
    }
#pragma unroll 4
    for (int k = 0; k < NHP; k += 4) {
      const float4 hv = *(const float4*)&hc[b][k];
#pragma unroll
      for (int jj = 0; jj < 2; ++jj) {
        const float4 wr = *(const float4*)&WhhP[jr[jj] * NHP + k];
        const float4 wz = *(const float4*)&WhhP[(NH + jr[jj]) * NHP + k];
        const float4 wn = *(const float4*)&WhhP[(2 * NH + jr[jj]) * NHP + k];
        hr2[jj] += wr.x*hv.x + wr.y*hv.y + wr.z*hv.z + wr.w*hv.w;
        hz2[jj] += wz.x*hv.x + wz.y*hv.y + wz.z*hv.z + wz.w*hv.w;
        hn2[jj] += wn.x*hv.x + wn.y*hv.y + wn.z*hv.z + wn.w*hv.w;
      }
    }
#pragma unroll
    for (int jj = 0; jj < 2; ++jj) {
      const float r = sigm(ar[jj] + hr2[jj]);
      const float z = sigm(az[jj] + hz2[jj]);
      const float n = ftanh(an[jj] + r * hn2[jj]);
      const float h2 = (1.f - z) * n + z * hc[b][jr[jj]];
      if (j0 + jj < NH) hx[b][j0 + jj] = h2;
    }
    __syncthreads();

    // phase 5: out = h2 @ h2o^T + b — one wave per batch row, shfl butterfly
    {
      const int w = tid >> 6;          // wave id = batch row
      const int l = tid & 63;
      const float2 hv = *(const float2*)&hx[w][2 * l];
      const float2 wv = *(const float2*)&hows[2 * l];
      float o = hv.x * wv.x + hv.y * wv.y;
#pragma unroll
      for (int mm = 1; mm < 64; mm <<= 1) o += __shfl_xor(o, mm, 64);
      if (l == 0) {
        const float r = o + hob0;
        out[s * NB + b0 + w] = r;
        prevs[w] = r;
      }
    }
    __syncthreads();
  }
}

extern "C" void kernel_launch(void* const* d_in, const int* in_sizes, int n_in,
                              void* d_out, int out_size, void* d_ws, size_t ws_size,
                              hipStream_t stream)
{
  const float* ann   = (const float*)d_in[0];
  const float* xenc  = (const float*)d_in[1];
  const float* xdec  = (const float*)d_in[2];
  const float* W1    = (const float*)d_in[3];
  const float* b1    = (const float*)d_in[4];
  const float* W2    = (const float*)d_in[5];
  const float* b2    = (const float*)d_in[6];
  const float* eWih  = (const float*)d_in[7];
  const float* eWhh  = (const float*)d_in[8];
  const float* ebih  = (const float*)d_in[9];
  const float* ebhh  = (const float*)d_in[10];
  const float* dWih  = (const float*)d_in[11];
  const float* dWhh  = (const float*)d_in[12];
  const float* dbih  = (const float*)d_in[13];
  const float* dbhh  = (const float*)d_in[14];
  const float* UW    = (const float*)d_in[15];
  const float* Ubias = (const float*)d_in[16];
  const float* Wl    = (const float*)d_in[17];
  const float* Wlb   = (const float*)d_in[18];
  const float* Vw    = (const float*)d_in[19];
  const float* Vb    = (const float*)d_in[20];
  const float* how   = (const float*)d_in[21];
  const float* hob   = (const float*)d_in[22];

  char* ws = (char*)d_ws;
  float* hstate = (float*)(ws + OFF_H);
  u16*   enc_o  = (u16*)(ws + OFF_ENC);
  u16*   uo_o   = (u16*)(ws + OFF_UO);
  float* pEWhh  = (float*)(ws + OFF_EWHH);
  float* pDWhh  = (float*)(ws + OFF_DWHH);
  float* pDWih  = (float*)(ws + OFF_DWIH);
  float* pUW    = (float*)(ws + OFF_UW);
  float* pWl    = (float*)(ws + OFF_WL);

  k_prep<<<720, 256, 0, stream>>>(eWhh, dWhh, dWih, UW, Wl, ws);
  k_mlp <<<128, 256, 0, stream>>>(ann, W1, b1, W2, b2, hstate);
  k_enc <<<512, 512, 0, stream>>>(xenc, eWih, ebih, ebhh, pEWhh, pUW, Ubias,
                                  hstate, enc_o, uo_o);
  k_dec <<<512, 512, 0, stream>>>(xdec, xenc, pDWih, pDWhh, dbih, dbhh,
                                  pWl, Wlb, Vw, Vb, how, hob, hstate,
                                  enc_o, uo_o, (float*)d_out);
}